// Round 6
// baseline (183.101 us; speedup 1.0000x reference)
//
#include <hip/hip_runtime.h>
#include <hip/hip_bf16.h>
#include <math.h>

// Problem constants (fixed by setup_inputs)
#define BATCH 4
#define NHEAD 8
#define HD 24          // head dim
#define CH 192         // total channels
#define HW 16384       // h*w
#define SPL 16         // kA col-blocks of 1024
#define SROW 640       // Sp row: [0,576) gram, [576,600) sqq, [600,624) sqk, pad 640

// ws layout (floats):
//   Sp:  [32 bh][16 sp][640]   off 0        (1.31 MB)
//   Mo:  ushort[4][192][192]   off OFF_MO   (288 KB)
//   cnt: uint[32]              off OFF_CNT  (zeroed via tiny memset each launch)
#define OFF_MO  (32 * SPL * SROW)
#define OFF_CNT (OFF_MO + (BATCH * CH * CH) / 2)

#define ASTR 260   // u32 per kA LDS row (256 data + 4 pad; same bank geometry as proven 132)

typedef __attribute__((ext_vector_type(8)))  short bf16x8;
typedef __attribute__((ext_vector_type(16))) float f32x16;

__device__ __forceinline__ unsigned short bf16rne(float x) {
    union { float f; unsigned u; } v; v.f = x;
    unsigned u = v.u;
    return (unsigned short)((u + 0x7FFFu + ((u >> 16) & 1u)) >> 16);
}

__device__ __forceinline__ unsigned pack2(float a, float b) {
    union { __hip_bfloat162 h; unsigned u; } c;
    c.h = __float22bfloat162_rn(float2{a, b});
    return c.u;
}

// Agent-scope RELAXED accessors (sc1, commit at L3; NO cache-flush fences).
__device__ __forceinline__ void st_agent(float* p, float v) {
    __hip_atomic_store(p, v, __ATOMIC_RELAXED, __HIP_MEMORY_SCOPE_AGENT);
}
__device__ __forceinline__ float ld_agent(const float* p) {
    return __hip_atomic_load(p, __ATOMIC_RELAXED, __HIP_MEMORY_SCOPE_AGENT);
}

// ---------------------------------------------------------------------------
// Kernel A + fenceless finalizer — ROW-MAJOR STREAMS. Per (bh, 1024-col
// block), two halves of 512 cols. Each wave owns 12 whole rows of the 48-row
// (q|k) stack and reads each row's 2 KB CONTIGUOUSLY (2 x 1KB wave-instrs
// back-to-back) before moving to the next row: long sequential DRAM bursts,
// ~8k concurrent streams instead of ~49k x 512B (R5 ran at 1.2 TB/s HBM with
// all pipes <4% -> DRAM row-buffer locality is the theory under test).
// Gram via mfma 32x32x16, k-split across waves. grid (32 bh, 16 cb),
// block 256, 2 blocks/CU (49.9 KB LDS).
// ---------------------------------------------------------------------------
__global__ __launch_bounds__(256, 2) void kA(const float* __restrict__ q,
                                             const float* __restrict__ k,
                                             const float* __restrict__ scale,
                                             const float* __restrict__ w,
                                             float* __restrict__ ws,
                                             unsigned short* __restrict__ Mo,
                                             unsigned int* __restrict__ cnt) {
    // Arena lifetimes (barrier-separated):
    //   staging: u32 [48 rows][ASTR]            = 49920 B
    //   reduce:  float [4][624]                 =  9984 B
    //   final:   float [5280] (SA|qinv|kinv|wl) = 21120 B
    __shared__ unsigned int arena[48 * ASTR];
    __shared__ int lastFlag;

    const int bh   = blockIdx.x;
    const int cb   = blockIdx.y;      // 0..15 -> cols [cb*1024, +1024)
    const int t    = threadIdx.x;
    const int lane = t & 63;
    const int wave = t >> 6;
    const int m    = lane & 31;
    const int hi   = lane >> 5;
    const int rowc = (m < HD) ? m : 0;   // clamp: garbage only hits discarded C

    const float* qb = q + (size_t)bh * HD * HW + cb * 1024;
    const float* kb = k + (size_t)bh * HD * HW + cb * 1024;

    f32x16 aQK = {}, aQQ = {}, aKK = {};

    #pragma unroll
    for (int half = 0; half < 2; ++half) {
        if (half) __syncthreads();      // prior MFMA done reading arena

        // Wave w streams rows w*12 .. w*12+12 of the 48-row (q|k) stack,
        // ROW-MAJOR: each row's 512 floats (2 KB) in 2 back-to-back 1KB
        // wave-instrs. Grouped 4 rows (8 loads in flight, 32 VGPR).
        #pragma unroll
        for (int grp = 0; grp < 3; ++grp) {
            float4 v[8];
            #pragma unroll
            for (int rr = 0; rr < 4; ++rr) {
                const int r48 = wave * 12 + grp * 4 + rr;
                const float* src = (r48 < 24) ? qb : kb;
                const int row = (r48 < 24) ? r48 : r48 - 24;
                #pragma unroll
                for (int i = 0; i < 2; ++i)
                    v[rr * 2 + i] = *(const float4*)(src + (size_t)row * HW +
                                                     half * 512 + i * 256 + lane * 4);
            }
            #pragma unroll
            for (int rr = 0; rr < 4; ++rr) {
                const int r48 = wave * 12 + grp * 4 + rr;
                #pragma unroll
                for (int i = 0; i < 2; ++i) {
                    float4 x = v[rr * 2 + i];
                    *(uint2*)&arena[r48 * ASTR + i * 128 + lane * 2] =
                        make_uint2(pack2(x.x, x.y), pack2(x.z, x.w));
                }
            }
        }
        __syncthreads();

        // k-split: wave w consumes k16-steps w*8 .. w*8+8 (128 cols).
        #pragma unroll
        for (int s = 0; s < 8; ++s) {
            const int k16 = wave * 8 + s;
            bf16x8 aq = *(const bf16x8*)&arena[rowc * ASTR + k16 * 8 + hi * 4];
            bf16x8 bk = *(const bf16x8*)&arena[(24 + rowc) * ASTR + k16 * 8 + hi * 4];
            aQK = __builtin_amdgcn_mfma_f32_32x32x16_bf16(aq, bk, aQK, 0, 0, 0);
            aQQ = __builtin_amdgcn_mfma_f32_32x32x16_bf16(aq, aq, aQQ, 0, 0, 0);
            aKK = __builtin_amdgcn_mfma_f32_32x32x16_bf16(bk, bk, aKK, 0, 0, 0);
        }
    }
    __syncthreads();   // all waves done reading arena -> overlay reduce

    float* red = (float*)arena;
    if (m < HD) {
        #pragma unroll
        for (int r = 0; r < 16; ++r) {
            const int i = (r & 3) + 8 * (r >> 2) + 4 * hi;
            if (i < HD) {
                red[wave * 624 + i * HD + m] = aQK[r];
                if (i == m) {
                    red[wave * 624 + 576 + i] = aQQ[r];
                    red[wave * 624 + 600 + i] = aKK[r];
                }
            }
        }
    }
    __syncthreads();

    float* Srow = ws + ((size_t)bh * SPL + cb) * SROW;
    for (int e = t; e < 624; e += 256)
        st_agent(&Srow[e], red[e] + red[624 + e] + red[1248 + e] + red[1872 + e]);

    // Per-wave drain: sc1 stores retire vmcnt at the L3 coherence point.
    asm volatile("s_waitcnt vmcnt(0)" ::: "memory");
    __syncthreads();   // all waves drained before t0's count increment

    if (t == 0) {
        unsigned int old = __hip_atomic_fetch_add(&cnt[bh], 1u,
                                                  __ATOMIC_RELAXED,
                                                  __HIP_MEMORY_SCOPE_AGENT);
        lastFlag = (old == SPL - 1);
    }
    __syncthreads();
    if (!lastFlag) return;

    // ---------------- finalizer (old kB), 256 threads, LDS reuse ----------
    // sf layout: [0,624) SA | [624,648) qinv | [648,672) kinv | [672,5280) wl
    float* sf = (float*)arena;
    const int b = bh >> 3;
    const int h = bh & 7;
    const float* base = ws + (size_t)bh * SPL * SROW;

    for (int idx = t; idx < CH * HD; idx += 256) {
        int o = idx / HD, dd = idx - o * HD;
        sf[672 + idx] = w[o * CH + h * HD + dd];
    }
    for (int e = t; e < 624; e += 256) {
        float s0 = 0.f, s1 = 0.f, s2 = 0.f, s3 = 0.f;
        #pragma unroll
        for (int sp = 0; sp < SPL; sp += 4) {
            s0 += ld_agent(&base[(size_t)(sp + 0) * SROW + e]);
            s1 += ld_agent(&base[(size_t)(sp + 1) * SROW + e]);
            s2 += ld_agent(&base[(size_t)(sp + 2) * SROW + e]);
            s3 += ld_agent(&base[(size_t)(sp + 3) * SROW + e]);
        }
        sf[e] = (s0 + s1) + (s2 + s3);
    }
    __syncthreads();

    if (t < 2 * HD) {
        float inv = 1.0f / fmaxf(sqrtf(sf[576 + t]), 1e-12f);
        sf[624 + t] = inv;                     // qinv at 624, kinv at 648
    }
    __syncthreads();

    const float sc = scale[h];
    for (int e = t; e < 576; e += 256)
        sf[e] = sf[e] * sf[624 + e / HD] * sf[648 + e % HD] * sc;
    __syncthreads();

    if (t < HD) {   // softmax along j for row t
        float mx = -1e30f;
        for (int j = 0; j < HD; ++j) mx = fmaxf(mx, sf[t * HD + j]);
        float sum = 0.f;
        for (int j = 0; j < HD; ++j) {
            float v = expf(sf[t * HD + j] - mx);
            sf[t * HD + j] = v;
            sum += v;
        }
        float r = 1.0f / sum;
        for (int j = 0; j < HD; ++j) sf[t * HD + j] *= r;
    }
    __syncthreads();

    // Mo[b][o][h*24+j] = (sum_i w[o,h*24+i] * attn[i][j]) * kinv[j]  (bf16)
    for (int idx = t; idx < CH * HD; idx += 256) {
        int o = idx / HD, j = idx - o * HD;
        float v = 0.f;
        #pragma unroll
        for (int i = 0; i < HD; ++i)
            v = fmaf(sf[672 + o * HD + i], sf[i * HD + j], v);
        Mo[(size_t)b * CH * CH + (size_t)o * CH + h * HD + j] = bf16rne(v * sf[648 + j]);
    }
}

// ---------------------------------------------------------------------------
// Kernel C — ROW-MAJOR STREAMS + 1KB STORES. out[b][o][n] = sum_c Mo[b][o][c]
// * in2[b][c][n], tile O=192 x N=256, 512 threads (8 waves), wave w owns
// n-tile w (32 n) x all 6 o-tiles. Reads: whole 1KB channel rows per
// wave-instr (channel PAIRS packed to bf16). Stores: per-32-o slice LDS
// transpose, then 1KB contiguous row stores (R5 wrote scattered 128B
// segments). grid (HW/256=64, 4 b), block 512, 1 block/CU (36.9 KB LDS).
// ---------------------------------------------------------------------------
#define KCN 256
#define BSTRC 36   // u32 per n-row (32 data + 4 pad; proven bank geometry)
#define TSTR 260   // float per transpose row (256 data + 4 pad)

__global__ __launch_bounds__(512, 2) void kC(const float* __restrict__ k,
                                             const unsigned short* __restrict__ Mo,
                                             float* __restrict__ out) {
    __shared__ unsigned int arena[KCN * BSTRC];   // 36.9 KB (transpose reuses)

    const int t    = threadIdx.x;
    const int lane = t & 63;
    const int wave = t >> 6;    // 0..7
    const int n31  = lane & 31;
    const int hi   = lane >> 5;

    const int nb = blockIdx.x * KCN;
    const int b  = blockIdx.y;

    const float* kb = k + (size_t)b * CH * HW;
    const unsigned short* Mob = Mo + (size_t)b * CH * CH;

    f32x16 acc[6] = {};

    #pragma unroll
    for (int s = 0; s < 3; ++s) {       // 3 c-stages of 64
        if (s) __syncthreads();         // prior MFMA done reading arena

        // Wave w loads channels s*64 + w*8 .. +8 as 4 PAIRS; each channel
        // row is one 1KB wave-instr (64 lanes x float4), pairs back-to-back.
        #pragma unroll
        for (int p = 0; p < 4; ++p) {
            const int c = s * 64 + wave * 8 + p * 2;
            float4 a0 = *(const float4*)(kb + (size_t)c * HW + nb + lane * 4);
            float4 a1 = *(const float4*)(kb + (size_t)(c + 1) * HW + nb + lane * 4);
            #pragma unroll
            for (int j = 0; j < 4; ++j)
                arena[(lane * 4 + j) * BSTRC + wave * 4 + p] =
                    pack2((&a0.x)[j], (&a1.x)[j]);
        }
        __syncthreads();

        #pragma unroll
        for (int kc = 0; kc < 4; ++kc) {
            bf16x8 Bf = *(const bf16x8*)&arena[(wave * 32 + n31) * BSTRC + kc * 8 + hi * 4];
            #pragma unroll
            for (int oi = 0; oi < 6; ++oi) {
                const unsigned short* ap =
                    Mob + (size_t)(oi * 32 + n31) * CH + s * 64 + kc * 16 + hi * 8;
                bf16x8 Af = *(const bf16x8*)ap;
                acc[oi] = __builtin_amdgcn_mfma_f32_32x32x16_bf16(Af, Bf, acc[oi], 0, 0, 0);
            }
        }
    }

    // Store: 6 o-slices of 32 rows. Dump acc -> LDS, read back row-major,
    // 1 KB contiguous store per o-row (wave w stores rows w*4..+4).
    float* Tr = (float*)arena;
    float* op = out + (size_t)b * CH * HW;
    #pragma unroll
    for (int oi = 0; oi < 6; ++oi) {
        __syncthreads();   // prior readers (MFMA or previous slice) done
        #pragma unroll
        for (int r = 0; r < 16; ++r) {
            const int orow = (r & 3) + 8 * (r >> 2) + 4 * hi;
            Tr[orow * TSTR + wave * 32 + n31] = acc[oi][r];
        }
        __syncthreads();
        #pragma unroll
        for (int rr = 0; rr < 4; ++rr) {
            const int orow = wave * 4 + rr;
            float4 val = *(const float4*)&Tr[orow * TSTR + lane * 4];
            *(float4*)(op + (size_t)(oi * 32 + orow) * HW + nb + lane * 4) = val;
        }
    }
}

extern "C" void kernel_launch(void* const* d_in, const int* in_sizes, int n_in,
                              void* d_out, int out_size, void* d_ws, size_t ws_size,
                              hipStream_t stream) {
    const float* in1   = (const float*)d_in[0];
    const float* in2   = (const float*)d_in[1];
    const float* scale = (const float*)d_in[2];
    const float* projw = (const float*)d_in[3];
    float* ws  = (float*)d_ws;   // needs ~1.7 MB
    float* out = (float*)d_out;
    unsigned short* Mo = (unsigned short*)(ws + OFF_MO);
    unsigned int* cnt  = (unsigned int*)(ws + OFF_CNT);

    // ws is poisoned each iteration by the harness -> zero the 32 semaphores.
    hipMemsetAsync((void*)cnt, 0, 32 * sizeof(unsigned int), stream);
    kA<<<dim3(32, SPL), 256, 0, stream>>>(in1, in2, scale, projw, ws, Mo, cnt);
    kC<<<dim3(HW / KCN, BATCH), 512, 0, stream>>>(in2, Mo, out);
}

// Round 7
// 174.423 us; speedup vs baseline: 1.0498x; 1.0498x over previous
//
#include <hip/hip_runtime.h>
#include <hip/hip_bf16.h>
#include <math.h>

// Problem constants (fixed by setup_inputs)
#define BATCH 4
#define NHEAD 8
#define HD 24          // head dim
#define CH 192         // total channels
#define HW 16384       // h*w
#define SPL 32         // kA col-blocks of 512 (2x256 cols accumulated in regs)
#define SROW 640       // Sp row: [0,576) gram, [576,600) sqq, [600,624) sqk, pad 640

// ws layout (floats):
//   Sp:  [32 bh][32 sp][640]   off 0        (2.62 MB)
//   Mo:  ushort[4][192][192]   off OFF_MO   (288 KB)
//   cnt: uint[32]              off OFF_CNT  (zeroed via tiny memset each launch)
#define OFF_MO  (32 * SPL * SROW)
#define OFF_CNT (OFF_MO + (BATCH * CH * CH) / 2)

#define LSTR 132   // u32 per kA LDS row (128 data + 4 pad)

typedef __attribute__((ext_vector_type(8)))  short bf16x8;
typedef __attribute__((ext_vector_type(16))) float f32x16;

__device__ __forceinline__ unsigned short bf16rne(float x) {
    union { float f; unsigned u; } v; v.f = x;
    unsigned u = v.u;
    return (unsigned short)((u + 0x7FFFu + ((u >> 16) & 1u)) >> 16);
}

__device__ __forceinline__ unsigned pack2(float a, float b) {
    union { __hip_bfloat162 h; unsigned u; } c;
    c.h = __float22bfloat162_rn(float2{a, b});
    return c.u;
}

// Agent-scope RELAXED accessors (sc1, commit at L3; NO cache-flush fences).
__device__ __forceinline__ void st_agent(float* p, float v) {
    __hip_atomic_store(p, v, __ATOMIC_RELAXED, __HIP_MEMORY_SCOPE_AGENT);
}
__device__ __forceinline__ float ld_agent(const float* p) {
    return __hip_atomic_load(p, __ATOMIC_RELAXED, __HIP_MEMORY_SCOPE_AGENT);
}

// ---------------------------------------------------------------------------
// Kernel A + fenceless finalizer — R4 VERBATIM except the window swizzle:
// window w = (blockIdx.y + bh) & 31. With x-fastest dispatch, the cohort of
// concurrently-running blocks (all bh at one blockIdx.y) previously read the
// SAME column window of every head (base addrs 1.5 MB apart = same channel
// residue, rows at 64 KB stride) -> narrow HBM channel subset active, ~1.2
// TB/s regardless of intra-block structure (R4/R5/R6 invariance). The
// swizzle makes each cohort span all 32 windows -> all channel residues.
// grid (32 bh, 32 w), block 256, 4/CU.
// ---------------------------------------------------------------------------
__global__ __launch_bounds__(256, 4) void kA(const float* __restrict__ q,
                                             const float* __restrict__ k,
                                             const float* __restrict__ scale,
                                             const float* __restrict__ w,
                                             float* __restrict__ ws,
                                             unsigned short* __restrict__ Mo,
                                             unsigned int* __restrict__ cnt) {
    __shared__ unsigned int tile[2][HD * LSTR];   // 25.3 KB (reused by finalizer)
    __shared__ int lastFlag;

    const int bh   = blockIdx.x;
    const int wn   = (blockIdx.y + bh) & 31;   // swizzled column window 0..31
    const int t    = threadIdx.x;
    const int lane = t & 63;
    const int wave = t >> 6;
    const int m    = lane & 31;
    const int hi   = lane >> 5;
    const int rowc = (m < HD) ? m : 0;   // clamp: garbage only hits discarded C

    f32x16 aQK = {}, aQQ = {}, aKK = {};

    #pragma unroll
    for (int half = 0; half < 2; ++half) {
        const float* qb = q + (size_t)bh * HD * HW + wn * 512 + half * 256;
        const float* kb = k + (size_t)bh * HD * HW + wn * 512 + half * 256;

        #pragma unroll
        for (int j = 0; j < 6; ++j) {
            const int idx = j * 256 + t;        // 0..1535
            const int row = idx >> 6;           // 0..23
            const int c64 = idx & 63;
            float4 qv = *(const float4*)(qb + (size_t)row * HW + c64 * 4);
            float4 kv = *(const float4*)(kb + (size_t)row * HW + c64 * 4);
            *(uint2*)&tile[0][row * LSTR + c64 * 2] =
                make_uint2(pack2(qv.x, qv.y), pack2(qv.z, qv.w));
            *(uint2*)&tile[1][row * LSTR + c64 * 2] =
                make_uint2(pack2(kv.x, kv.y), pack2(kv.z, kv.w));
        }
        __syncthreads();

        #pragma unroll
        for (int s = 0; s < 4; ++s) {
            const int off = (wave * 64 + s * 16) >> 1;
            bf16x8 aq = *(const bf16x8*)&tile[0][rowc * LSTR + off + hi * 4];
            bf16x8 bk = *(const bf16x8*)&tile[1][rowc * LSTR + off + hi * 4];
            aQK = __builtin_amdgcn_mfma_f32_32x32x16_bf16(aq, bk, aQK, 0, 0, 0);
            aQQ = __builtin_amdgcn_mfma_f32_32x32x16_bf16(aq, aq, aQQ, 0, 0, 0);
            aKK = __builtin_amdgcn_mfma_f32_32x32x16_bf16(bk, bk, aKK, 0, 0, 0);
        }
        __syncthreads();   // LDS reuse (next half's staging / reduce scatter)
    }

    float* red = (float*)tile;
    if (m < HD) {
        #pragma unroll
        for (int r = 0; r < 16; ++r) {
            const int i = (r & 3) + 8 * (r >> 2) + 4 * hi;
            if (i < HD) {
                red[wave * 624 + i * HD + m] = aQK[r];
                if (i == m) {
                    red[wave * 624 + 576 + i] = aQQ[r];
                    red[wave * 624 + 600 + i] = aKK[r];
                }
            }
        }
    }
    __syncthreads();

    float* Srow = ws + ((size_t)bh * SPL + wn) * SROW;
    for (int e = t; e < 624; e += 256)
        st_agent(&Srow[e], red[e] + red[624 + e] + red[1248 + e] + red[1872 + e]);

    // Per-wave drain: sc1 stores retire vmcnt at the L3 coherence point.
    asm volatile("s_waitcnt vmcnt(0)" ::: "memory");
    __syncthreads();   // all waves drained before t0's count increment

    if (t == 0) {
        unsigned int old = __hip_atomic_fetch_add(&cnt[bh], 1u,
                                                  __ATOMIC_RELAXED,
                                                  __HIP_MEMORY_SCOPE_AGENT);
        lastFlag = (old == SPL - 1);
    }
    __syncthreads();
    if (!lastFlag) return;

    // ---------------- finalizer (old kB), 256 threads, LDS reuse ----------
    // sf layout: [0,624) SA | [624,648) qinv | [648,672) kinv | [672,5280) wl
    float* sf = (float*)tile;
    const int b = bh >> 3;
    const int h = bh & 7;
    const float* base = ws + (size_t)bh * SPL * SROW;

    for (int idx = t; idx < CH * HD; idx += 256) {
        int o = idx / HD, dd = idx - o * HD;
        sf[672 + idx] = w[o * CH + h * HD + dd];
    }
    for (int e = t; e < 624; e += 256) {
        float s0 = 0.f, s1 = 0.f, s2 = 0.f, s3 = 0.f;
        #pragma unroll
        for (int sp = 0; sp < SPL; sp += 4) {
            s0 += ld_agent(&base[(size_t)(sp + 0) * SROW + e]);
            s1 += ld_agent(&base[(size_t)(sp + 1) * SROW + e]);
            s2 += ld_agent(&base[(size_t)(sp + 2) * SROW + e]);
            s3 += ld_agent(&base[(size_t)(sp + 3) * SROW + e]);
        }
        sf[e] = (s0 + s1) + (s2 + s3);
    }
    __syncthreads();

    if (t < 2 * HD) {
        float inv = 1.0f / fmaxf(sqrtf(sf[576 + t]), 1e-12f);
        sf[624 + t] = inv;                     // qinv at 624, kinv at 648
    }
    __syncthreads();

    const float sc = scale[h];
    for (int e = t; e < 576; e += 256)
        sf[e] = sf[e] * sf[624 + e / HD] * sf[648 + e % HD] * sc;
    __syncthreads();

    if (t < HD) {   // softmax along j for row t
        float mx = -1e30f;
        for (int j = 0; j < HD; ++j) mx = fmaxf(mx, sf[t * HD + j]);
        float sum = 0.f;
        for (int j = 0; j < HD; ++j) {
            float v = expf(sf[t * HD + j] - mx);
            sf[t * HD + j] = v;
            sum += v;
        }
        float r = 1.0f / sum;
        for (int j = 0; j < HD; ++j) sf[t * HD + j] *= r;
    }
    __syncthreads();

    // Mo[b][o][h*24+j] = (sum_i w[o,h*24+i] * attn[i][j]) * kinv[j]  (bf16)
    for (int idx = t; idx < CH * HD; idx += 256) {
        int o = idx / HD, j = idx - o * HD;
        float v = 0.f;
        #pragma unroll
        for (int i = 0; i < HD; ++i)
            v = fmaf(sf[672 + o * HD + i], sf[i * HD + j], v);
        Mo[(size_t)b * CH * CH + (size_t)o * CH + h * HD + j] = bf16rne(v * sf[648 + j]);
    }
}

// ---------------------------------------------------------------------------
// Kernel C — R4 VERBATIM (control arm). out[b][o][n] = sum_c Mo[b][o][c] *
// in2[b][c][n] via mfma_32x32x16, tile O=192 x N=64, whole 64n x 192c tile
// staged in one shot (12 float4 loads/thread), one barrier, 36 MFMAs.
// grid (256 nblk, 4 b), block 256, 4/CU.
// ---------------------------------------------------------------------------
#define KCN 64
#define BSTR3 100   // u32 per n-row: 96 data (192 ch as bf16 pairs) + 4 pad

__global__ __launch_bounds__(256, 4) void kC(const float* __restrict__ k,
                                             const unsigned short* __restrict__ Mo,
                                             float* __restrict__ out) {
    __shared__ unsigned int Bt[KCN * BSTR3];   // 25.6 KB

    const int t    = threadIdx.x;
    const int lane = t & 63;
    const int wave = t >> 6;
    const int n31  = lane & 31;
    const int hi   = lane >> 5;
    const int nt   = wave & 1;          // n-tile (x32)
    const int otb  = (wave >> 1) * 3;   // first o-tile (x32) of this wave

    const int nb = blockIdx.x * KCN;
    const int b  = blockIdx.y;

    const float* kb = k + (size_t)b * CH * HW;
    const unsigned short* Mob = Mo + (size_t)b * CH * CH;

    const int np4 = t & 15;   // n-quad: rows np4*4 .. +3
    const int cg4 = t >> 4;   // 0..15: channels cg4*4 .. +3 per 64-ch stage

    // Stage the whole 64 x 192 tile (fp32 -> bf16 pairs), one barrier.
    #pragma unroll
    for (int s = 0; s < 3; ++s) {
        float4 v[4];
        #pragma unroll
        for (int cc = 0; cc < 4; ++cc)
            v[cc] = *(const float4*)(kb + (size_t)(s * 64 + cg4 * 4 + cc) * HW + nb + np4 * 4);
        #pragma unroll
        for (int r = 0; r < 4; ++r) {
            float x0 = (&v[0].x)[r], x1 = (&v[1].x)[r];
            float x2 = (&v[2].x)[r], x3 = (&v[3].x)[r];
            *(uint2*)&Bt[(np4 * 4 + r) * BSTR3 + s * 32 + cg4 * 2] =
                make_uint2(pack2(x0, x1), pack2(x2, x3));
        }
    }
    __syncthreads();

    f32x16 acc[3] = {};
    #pragma unroll
    for (int kc = 0; kc < 12; ++kc) {
        bf16x8 Bf = *(const bf16x8*)&Bt[(nt * 32 + n31) * BSTR3 + kc * 8 + hi * 4];
        #pragma unroll
        for (int oi = 0; oi < 3; ++oi) {
            const unsigned short* ap =
                Mob + (size_t)((otb + oi) * 32 + n31) * CH + kc * 16 + hi * 8;
            bf16x8 Af = *(const bf16x8*)ap;
            acc[oi] = __builtin_amdgcn_mfma_f32_32x32x16_bf16(Af, Bf, acc[oi], 0, 0, 0);
        }
    }

    float* op = out + (size_t)b * CH * HW;
    const int n = nb + nt * 32 + n31;
    #pragma unroll
    for (int oi = 0; oi < 3; ++oi)
        #pragma unroll
        for (int r = 0; r < 16; ++r) {
            int o = (otb + oi) * 32 + (r & 3) + 8 * (r >> 2) + 4 * hi;
            op[(size_t)o * HW + n] = acc[oi][r];
        }
}

extern "C" void kernel_launch(void* const* d_in, const int* in_sizes, int n_in,
                              void* d_out, int out_size, void* d_ws, size_t ws_size,
                              hipStream_t stream) {
    const float* in1   = (const float*)d_in[0];
    const float* in2   = (const float*)d_in[1];
    const float* scale = (const float*)d_in[2];
    const float* projw = (const float*)d_in[3];
    float* ws  = (float*)d_ws;   // needs ~2.9 MB
    float* out = (float*)d_out;
    unsigned short* Mo = (unsigned short*)(ws + OFF_MO);
    unsigned int* cnt  = (unsigned int*)(ws + OFF_CNT);

    // ws is poisoned each iteration by the harness -> zero the 32 semaphores.
    hipMemsetAsync((void*)cnt, 0, 32 * sizeof(unsigned int), stream);
    kA<<<dim3(32, SPL), 256, 0, stream>>>(in1, in2, scale, projw, ws, Mo, cnt);
    kC<<<dim3(HW / KCN, BATCH), 256, 0, stream>>>(in2, Mo, out);
}